// Round 6
// baseline (9516.946 us; speedup 1.0000x reference)
//
#include <hip/hip_runtime.h>

// GRU scan, 2 layers, B=64 T=4096 D=H=128 — cross-WG layer pipeline.
// 8 WGs = 4 batch-slices x {A = layer-0 recurrence, C = layer-1 recurrence}.
// A streams h0(t) bf16 B-frag blocks into a d_ws ring (8 slots, agent-scope
// atomics -> coherent at L3); C loads them straight into MFMA B-operand regs
// (2-step prefetch). Per WG: 4 gate-elements/lane (half of R5), 24 MFMA/wave.
// Step shape (R3-proven sandwich): ds_read h -> hh-MFMA -> gates -> commit ->
// ih-MFMA(t+1) from registers -> one barrier.
// Sync: flag[slot]=t+1 released by tid0 after the barrier that drains the
// data stores; C acquires. Pacing: C publishes consumed counter; A throttles
// to window 4 (ring 8) -> no lapping. All spins capped (no hangs).

#define Tlen 4096
#define Hd   128
#define Bsz  64
#define RING 8
#define SPIN_CAP (1L << 22)

typedef __attribute__((ext_vector_type(8))) short short8;
typedef __attribute__((ext_vector_type(4))) short short4v;
typedef __attribute__((ext_vector_type(4))) float float4v;
typedef __attribute__((ext_vector_type(2))) unsigned int uint2v;
typedef __attribute__((ext_vector_type(4))) unsigned int uint4v;
typedef __attribute__((ext_vector_type(2))) unsigned long long ulong2v;

#define MFMA16(a, b, c) __builtin_amdgcn_mfma_f32_16x16x32_bf16((a), (b), (c), 0, 0, 0)

static __device__ __forceinline__ float fast_exp2(float x) {
#if __has_builtin(__builtin_amdgcn_exp2f)
  return __builtin_amdgcn_exp2f(x);
#else
  return exp2f(x);
#endif
}
static __device__ __forceinline__ float fast_rcp(float x) {
  return __builtin_amdgcn_rcpf(x);
}
static __device__ __forceinline__ short f2bf(float f) {
  unsigned u = __builtin_bit_cast(unsigned, f);
  u = (u + 0x7FFFu + ((u >> 16) & 1u)) >> 16;
  return (short)u;
}
static __device__ __forceinline__ unsigned pk2bf(float a, float b) {
#if __has_builtin(__builtin_amdgcn_cvt_pk_bf16_f32)
  auto v = __builtin_amdgcn_cvt_pk_bf16_f32(a, b);
  return __builtin_bit_cast(unsigned, v);
#else
  return (unsigned)(unsigned short)f2bf(a) | ((unsigned)(unsigned short)f2bf(b) << 16);
#endif
}
static __device__ __forceinline__ short8 loadw8(const float* __restrict__ p) {
  short8 r;
  #pragma unroll
  for (int j = 0; j < 8; ++j) r[j] = f2bf(p[j]);
  return r;
}

// Frag-linear block (2048 shorts): addr(b,k) = (k>>5)*512+((k>>3)&3)*128+b*8+(k&7)
// Reader lane l, kstep s: 16B at shorts s*512 + l*8 (conflict-free).

#define IH_MFMA(bf)                                            \
  {                                                            \
    aR  = MFMA16(wxr[0], bf[0], Z4);                           \
    aZ  = MFMA16(wxz[0], bf[0], Z4);                           \
    aIN = MFMA16(wxn[0], bf[0], Z4);                           \
    _Pragma("unroll")                                          \
    for (int s = 1; s < 4; ++s) {                              \
      aR  = MFMA16(wxr[s], bf[s], aR);                         \
      aZ  = MFMA16(wxz[s], bf[s], aZ);                         \
      aIN = MFMA16(wxn[s], bf[s], aIN);                        \
    }                                                          \
  }

#define HH_MFMA(hf)                                            \
  {                                                            \
    aHN = MFMA16(whn[0], hf[0], Z4);                           \
    aR  = MFMA16(whr[0], hf[0], aR);                           \
    aZ  = MFMA16(whz[0], hf[0], aZ);                           \
    _Pragma("unroll")                                          \
    for (int s = 1; s < 4; ++s) {                              \
      aHN = MFMA16(whn[s], hf[s], aHN);                        \
      aR  = MFMA16(whr[s], hf[s], aR);                         \
      aZ  = MFMA16(whz[s], hf[s], aZ);                         \
    }                                                          \
  }

#define GATES()                                                            \
  {                                                                        \
    _Pragma("unroll")                                                      \
    for (int i = 0; i < 4; ++i) {                                          \
      const float er = fast_exp2(fmaf(aR[i], nL, kr[i]));                  \
      const float rr = fast_rcp(1.0f + er);                                \
      const float ez = fast_exp2(fmaf(aZ[i], nL, kz[i]));                  \
      const float zz = fast_rcp(1.0f + ez);                                \
      const float vv = fmaf(rr, fmaf(aHN[i], n2L, kh[i]),                  \
                            fmaf(aIN[i], n2L, ki[i]));                     \
      const float e2 = fast_exp2(vv);                                      \
      const float nn = fmaf(2.0f, fast_rcp(1.0f + e2), -1.0f);             \
      hn[i] = fmaf(zz, hp[i] - nn, nn);                                    \
      hp[i] = hn[i];                                                       \
    }                                                                      \
  }

__global__ __launch_bounds__(512, 2) void gru_pipe(
    const float* __restrict__ x,
    const float* __restrict__ Wih0, const float* __restrict__ Whh0,
    const float* __restrict__ bih0, const float* __restrict__ bhh0,
    const float* __restrict__ Wih1, const float* __restrict__ Whh1,
    const float* __restrict__ bih1, const float* __restrict__ bhh1,
    float* __restrict__ out, char* __restrict__ ws) {
  __shared__ alignas(16) short Hbuf[4096];  // 2 x 2048 (double-buffered h)

  const int tid   = threadIdx.x;
  const int w     = tid >> 6;
  const int lane  = tid & 63;
  const int lc    = lane & 15;
  const int quad  = lane >> 4;
  const int q8    = quad * 8;
  const int lane8 = lane * 8;
  const int role  = (int)blockIdx.x & 1;     // 0 = layer0 (A), 1 = layer1 (C)
  const int slice = (int)blockIdx.x >> 1;
  const int bbase = slice * 16;

  char* ring = ws + (size_t)slice * 65536;             // 8 slots x 8192 B
  int*  F    = (int*)(ws + 0x40000 + (size_t)slice * 1024);  // flags[0..7], cons=F[64]

  const int wroff = (w >> 1) * 512 + ((2 * w + (quad >> 1)) & 3) * 128 +
                    lc * 8 + 4 * (quad & 1);
  const float nL  = -1.44269504088896f;
  const float n2L = -2.88539008177793f;
  const float4v Z4 = {0.f, 0.f, 0.f, 0.f};

  // ---- stationary weights for this role's layer ---------------------------
  const float* Wi = role ? Wih1 : Wih0;
  const float* Wh = role ? Whh1 : Whh0;
  const float* bi = role ? bih1 : bih0;
  const float* bh = role ? bhh1 : bhh0;

  short8 wxr[4], wxz[4], wxn[4], whr[4], whz[4], whn[4];
  #pragma unroll
  for (int s = 0; s < 4; ++s) {
    const int k = 32 * s + q8;
    wxr[s] = loadw8(Wi + (16 * w + lc) * Hd + k);
    wxz[s] = loadw8(Wi + (128 + 16 * w + lc) * Hd + k);
    wxn[s] = loadw8(Wi + (256 + 16 * w + lc) * Hd + k);
    whr[s] = loadw8(Wh + (16 * w + lc) * Hd + k);
    whz[s] = loadw8(Wh + (128 + 16 * w + lc) * Hd + k);
    whn[s] = loadw8(Wh + (256 + 16 * w + lc) * Hd + k);
  }
  float kr[4], kz[4], ki[4], kh[4];
  #pragma unroll
  for (int i = 0; i < 4; ++i) {
    const int u = 16 * w + quad * 4 + i;
    kr[i] = nL  * (bi[u] + bh[u]);
    kz[i] = nL  * (bi[128 + u] + bh[128 + u]);
    ki[i] = n2L * bi[256 + u];
    kh[i] = n2L * bh[256 + u];
  }

  {  // zero LDS (h(-1) = 0)
    int* zb = (int*)Hbuf;
    zb[tid] = 0; zb[tid + 512] = 0; zb[tid + 1024] = 0; zb[tid + 1536] = 0;
  }
  __syncthreads();

  float hp[4] = {0.f, 0.f, 0.f, 0.f};
  float hn[4];
  float4v aR, aZ, aIN, aHN;
  short8 bf[4];

  if (role == 0) {
    // ====================== A: layer-0 recurrence ======================
    const float* xg = x + (size_t)(bbase + lc) * (Tlen * Hd) + q8;
    float4v xf[8];

    #define XLOAD(T)                                                     \
      {                                                                  \
        const float* p = xg + (size_t)(T) * Hd;                          \
        _Pragma("unroll")                                                \
        for (int s = 0; s < 4; ++s) {                                    \
          xf[2 * s]     = *(const float4v*)(p + 32 * s);                 \
          xf[2 * s + 1] = *(const float4v*)(p + 32 * s + 4);             \
        }                                                                \
      }
    #define XCVT()                                                       \
      {                                                                  \
        _Pragma("unroll")                                                \
        for (int s = 0; s < 4; ++s) {                                    \
          uint4v u = {pk2bf(xf[2 * s][0], xf[2 * s][1]),                 \
                      pk2bf(xf[2 * s][2], xf[2 * s][3]),                 \
                      pk2bf(xf[2 * s + 1][0], xf[2 * s + 1][1]),         \
                      pk2bf(xf[2 * s + 1][2], xf[2 * s + 1][3])};        \
          bf[s] = __builtin_bit_cast(short8, u);                         \
        }                                                                \
      }

    XLOAD(0) XCVT()
    IH_MFMA(bf)          // accs hold ih(0)
    XLOAD(1)

    for (int t = 0; t < Tlen; ++t) {
      if (tid == 0 && t >= 1)   // h0(t-1) stores drained by last barrier
        __hip_atomic_store(&F[(t - 1) & 7], t, __ATOMIC_RELEASE,
                           __HIP_MEMORY_SCOPE_AGENT);
      if ((t & 3) == 0 && t >= RING) {  // pacing: keep lead <= ~7
        long spin = 0;
        while (__hip_atomic_load(&F[64], __ATOMIC_RELAXED,
                                 __HIP_MEMORY_SCOPE_AGENT) < t - 3 &&
               ++spin < SPIN_CAP) {}
      }
      short8 hf[4];
      #pragma unroll
      for (int s = 0; s < 4; ++s)
        hf[s] = *(const short8*)&Hbuf[((t + 1) & 1) * 2048 + s * 512 + lane8];
      HH_MFMA(hf)
      GATES()
      const uint2v pp = {pk2bf(hn[0], hn[1]), pk2bf(hn[2], hn[3])};
      *(short4v*)&Hbuf[(t & 1) * 2048 + wroff] = __builtin_bit_cast(short4v, pp);
      __hip_atomic_store(
          (unsigned long long*)(ring + (size_t)(t & 7) * 8192 + wroff * 2),
          __builtin_bit_cast(unsigned long long, pp), __ATOMIC_RELAXED,
          __HIP_MEMORY_SCOPE_AGENT);
      XCVT()              // x(t+1) -> frags
      IH_MFMA(bf)         // accs for t+1
      XLOAD(t + 2 < Tlen ? t + 2 : Tlen - 1)
      __syncthreads();
    }
    if (tid == 0)
      __hip_atomic_store(&F[(Tlen - 1) & 7], Tlen, __ATOMIC_RELEASE,
                         __HIP_MEMORY_SCOPE_AGENT);
    #pragma unroll
    for (int i = 0; i < 4; ++i)
      out[(bbase + lc) * Hd + 16 * w + quad * 4 + i] = hp[i];

  } else {
    // ====================== C: layer-1 recurrence ======================
    unsigned long long hra[8], hrb[8];  // even slots -> hra, odd -> hrb

    #define POLLW(T)                                                       \
      {                                                                    \
        long spin = 0;                                                     \
        const int want = (T) + 1;                                          \
        while (__hip_atomic_load(&F[(T) & 7], __ATOMIC_ACQUIRE,            \
                                 __HIP_MEMORY_SCOPE_AGENT) != want &&      \
               ++spin < SPIN_CAP) {}                                       \
      }
    #define H0LOAD(T, dst)                                                 \
      {                                                                    \
        const char* sb = ring + (size_t)((T) & 7) * 8192 + lane * 16;      \
        _Pragma("unroll")                                                  \
        for (int s = 0; s < 4; ++s) {                                      \
          dst[2 * s] = __hip_atomic_load(                                  \
              (const unsigned long long*)(sb + s * 1024),                  \
              __ATOMIC_RELAXED, __HIP_MEMORY_SCOPE_AGENT);                 \
          dst[2 * s + 1] = __hip_atomic_load(                              \
              (const unsigned long long*)(sb + s * 1024 + 8),              \
              __ATOMIC_RELAXED, __HIP_MEMORY_SCOPE_AGENT);                 \
        }                                                                  \
      }
    #define ASSEMBLE(src)                                                  \
      {                                                                    \
        _Pragma("unroll")                                                  \
        for (int s = 0; s < 4; ++s) {                                      \
          ulong2v uu = {src[2 * s], src[2 * s + 1]};                       \
          bf[s] = __builtin_bit_cast(short8, uu);                          \
        }                                                                  \
      }

    POLLW(0) H0LOAD(0, hra)
    ASSEMBLE(hra)
    IH_MFMA(bf)          // accs hold ih(0) = Wih1 . h0(0)
    POLLW(1) H0LOAD(1, hrb)

    for (int t = 0; t < Tlen; ++t) {
      if (tid == 0)       // consumed counter (loads <= t+1 retired)
        __hip_atomic_store(&F[64], t + 1, __ATOMIC_RELAXED,
                           __HIP_MEMORY_SCOPE_AGENT);
      short8 hf[4];
      #pragma unroll
      for (int s = 0; s < 4; ++s)
        hf[s] = *(const short8*)&Hbuf[((t + 1) & 1) * 2048 + s * 512 + lane8];
      HH_MFMA(hf)
      GATES()
      const uint2v pp = {pk2bf(hn[0], hn[1]), pk2bf(hn[2], hn[3])};
      *(short4v*)&Hbuf[(t & 1) * 2048 + wroff] = __builtin_bit_cast(short4v, pp);
      if (t + 1 < Tlen) {
        if (t & 1) { ASSEMBLE(hra) } else { ASSEMBLE(hrb) }
        IH_MFMA(bf)       // accs for t+1
      }
      if (t + 2 < Tlen) {
        POLLW(t + 2)
        if (t & 1) { H0LOAD(t + 2, hrb) } else { H0LOAD(t + 2, hra) }
      }
      __syncthreads();
    }
    #pragma unroll
    for (int i = 0; i < 4; ++i)
      out[Bsz * Hd + (bbase + lc) * Hd + 16 * w + quad * 4 + i] = hp[i];
  }
}

extern "C" void kernel_launch(void* const* d_in, const int* in_sizes, int n_in,
                              void* d_out, int out_size, void* d_ws, size_t ws_size,
                              hipStream_t stream) {
  (void)in_sizes; (void)n_in; (void)out_size; (void)ws_size;
  gru_pipe<<<8, 512, 0, stream>>>(
      (const float*)d_in[0],
      (const float*)d_in[1], (const float*)d_in[2],
      (const float*)d_in[3], (const float*)d_in[4],
      (const float*)d_in[5], (const float*)d_in[6],
      (const float*)d_in[7], (const float*)d_in[8],
      (float*)d_out, (char*)d_ws);
}